// Round 10
// baseline (334.642 us; speedup 1.0000x reference)
//
#include <hip/hip_runtime.h>
#include <hip/hip_bf16.h>
#include <math.h>

#define S_LEN 2048
#define HID_DIM 2048
#define NH 32
#define NOPE 128
#define ROPE_D 64
#define QKD 192           // NOPE + ROPE
#define VD 128
#define KV_RANK 512
#define SW 128
#define NQK (NH*QKD)      // 6144
#define CKV_N (KV_RANK+ROPE_D) // 576
#define KVN (NH*(NOPE+VD))     // 8192
#define KNW (NH*NOPE)          // 4096
#define OUT_HID 2048
#define ATT_SCALE 0.07216878364870323f  // 192^-0.5
#define NEG_INF (-1e30f)

typedef __bf16 bf16x8 __attribute__((ext_vector_type(8)));
typedef float  f32x4  __attribute__((ext_vector_type(4)));

// ---------------------------------------------------------------------------
// async global->LDS, 16B per lane. LDS dest = wave-uniform base + lane*16.
// ---------------------------------------------------------------------------
__device__ __forceinline__ void async_load16(const void* gp, void* lp) {
    __builtin_amdgcn_global_load_lds(
        (const __attribute__((address_space(1))) void*)gp,
        (__attribute__((address_space(3))) void*)lp, 16, 0, 0);
}

// ---------------------------------------------------------------------------
// prep: hidden cvt + Wq/Wkva transposes + BOTTOM half of Wo (tiles 1024..2047,
// rows 2048..4095). Top half of Wo rides in gemm_q_ckv's tail (R9 rebalance:
// tail = Wkvb 25 MB + Wo-half 25 MB = 50 MB ~ 52 us < 71 us GEMM, hides).
// float4 reads (R4), ushort4 transpose stores (R7).
// ---------------------------------------------------------------------------
__global__ __launch_bounds__(256)
void prep(const float* __restrict__ hidden, __hip_bfloat16* __restrict__ hid_bf,
          const float* __restrict__ Wq,   __hip_bfloat16* __restrict__ WqT,
          const float* __restrict__ Wkva, __hip_bfloat16* __restrict__ WkvaT,
          const float* __restrict__ Wo,   __hip_bfloat16* __restrict__ WoT)
{
    __shared__ float tile[64][65];
    int b = blockIdx.x;
    const int t = threadIdx.x;

    if (b < 4096) {
        int i = b * 256 + t;
        float4 v = ((const float4*)hidden)[i];
        hid_bf[i * 4 + 0] = __float2bfloat16(v.x);
        hid_bf[i * 4 + 1] = __float2bfloat16(v.y);
        hid_bf[i * 4 + 2] = __float2bfloat16(v.z);
        hid_bf[i * 4 + 3] = __float2bfloat16(v.w);
        return;
    }
    b -= 4096;
    const float* src; __hip_bfloat16* dst; int rows, cols, CX;
    if (b < 3072)               { src = Wq;   dst = WqT;   rows = 2048; cols = 6144; CX = 96; }
    else if ((b -= 3072) < 288) { src = Wkva; dst = WkvaT; rows = 2048; cols = 576;  CX = 9;  }
    else { b -= 288; b += 1024;   src = Wo;   dst = WoT;   rows = 4096; cols = 2048; CX = 32; }

    const int bx = b % CX, by = b / CX;
    const int r0 = by * 64, c0 = bx * 64;

    // read: float4 per thread, 4 row-groups of 16 lanes x 256B contiguous
    {
        const int r  = t >> 4;          // 0..15
        const int c4 = (t & 15) * 4;    // 0,4,..,60
        #pragma unroll
        for (int i = 0; i < 4; ++i) {
            const int rr = r + i * 16;
            float4 v = *(const float4*)&src[(size_t)(r0 + rr) * cols + c0 + c4];
            tile[rr][c4 + 0] = v.x;
            tile[rr][c4 + 1] = v.y;
            tile[rr][c4 + 2] = v.z;
            tile[rr][c4 + 3] = v.w;
        }
    }
    __syncthreads();
    // write: ushort4 per thread (4 consecutive dst cols = src rows, fixed dr)
    {
        const int tx0 = (t & 15) * 4;   // src-row group -> dst cols
        const int drb = t >> 4;         // 0..15
        #pragma unroll
        for (int i = 0; i < 4; ++i) {
            const int dr = drb + i * 16;            // src col = dst row
            __hip_bfloat16 b0 = __float2bfloat16(tile[tx0 + 0][dr]);
            __hip_bfloat16 b1 = __float2bfloat16(tile[tx0 + 1][dr]);
            __hip_bfloat16 b2 = __float2bfloat16(tile[tx0 + 2][dr]);
            __hip_bfloat16 b3 = __float2bfloat16(tile[tx0 + 3][dr]);
            ushort4 pk;
            pk.x = *(unsigned short*)&b0; pk.y = *(unsigned short*)&b1;
            pk.z = *(unsigned short*)&b2; pk.w = *(unsigned short*)&b3;
            *(ushort4*)&dst[(size_t)(c0 + dr) * rows + r0 + tx0] = pk;
        }
    }
}

// ---------------------------------------------------------------------------
// 256x256 8-phase bf16 GEMM core (T2 swizzle + T3/T4 counted vmcnt + T5).
//   BM=BN=256, BK=64, 8 waves (2M x 4N), per-wave output 128x64.
//   LDS 128 KiB: 2 buffers x (A 256x64 + B 256x64) bf16.
//   Bank swizzle: physical 16B-chunk = logical_chunk ^ (row & 7), applied on
//   the global SOURCE (stage) and the ds_read address; LDS dest linear.
//   Liveness: B half-tiles read at phases 1-2, A at phases 1,3 =>
//     P3: B0 | P4: B1,A0 + vmcnt(6) | P5: A1  (mirrored P7/P8/P1').
//   R4 lesson: drain is STG -> VMC(6) -> BAR -> MMQ (moving VMC after MMQ
//   regressed 20%). R7 lesson: XCD swizzle HURTS here (fully-resident grid:
//   natural round-robin keeps 3 B-panels/XCD L2-resident; swizzle thrashed).
// ---------------------------------------------------------------------------
#define BAR()   __builtin_amdgcn_s_barrier()
#define LGKM0() asm volatile("s_waitcnt lgkmcnt(0)" ::: "memory")
#define VMC(n)  asm volatile("s_waitcnt vmcnt(" #n ")" ::: "memory")

__device__ __forceinline__ void gemm256_core(
    const __hip_bfloat16* __restrict__ A, int lda,
    const __hip_bfloat16* __restrict__ Bt, int ldbt,
    int m0, int n0, int kbeg, int nit,
    __hip_bfloat16* lds, f32x4 (&acc)[8][4])
{
    const int t = threadIdx.x;
    const int w = t >> 6, L = t & 63;
    const int lane15 = L & 15, quad = L >> 4;
    const int wr = w >> 2, wc = w & 3;

    // staging addressing: wave w, load i covers physical rows w*8+i*64 ..+8
    const int prw = w * 8 + (L >> 3);                 // row, load i=0
    const int c8  = ((L & 7) ^ ((L >> 3) & 7)) * 8;   // inverse-swizzled k-chunk (elems)
    const __hip_bfloat16* gA = A  + (size_t)(m0 + prw) * lda  + kbeg + c8;
    const __hip_bfloat16* gB = Bt + (size_t)(n0 + prw) * ldbt + kbeg + c8;
    const int uA = w * 512;              // elem offset; +buf*32768 +h*8192 (+4096 i=1)
    const int uB = 16384 + w * 512;

    // read addressing (swizzled chunk per lane; row%8 == lane15%8 always)
    const int cx0 = ((quad)     ^ (L & 7)) * 8;       // ks=0
    const int cx1 = ((4 + quad) ^ (L & 7)) * 8;       // ks=1
    const int ra  = wr * 8192 + lane15 * 64;                                  // A
    const int rb  = 16384 + (wc >> 1) * 8192 + (wc & 1) * 4096 + lane15 * 64; // B

    bf16x8 af[4][2], bfr[4][2];

    auto STG_A = [&](int buf, int h, int kt) {
        const __hip_bfloat16* g = gA + (size_t)h * 128 * lda + kt * 64;
        __hip_bfloat16* lp = lds + buf * 32768 + h * 8192 + uA;
        async_load16(g, lp);
        async_load16(g + (size_t)64 * lda, lp + 4096);
    };
    auto STG_B = [&](int buf, int h, int kt) {
        const __hip_bfloat16* g = gB + (size_t)h * 128 * ldbt + kt * 64;
        __hip_bfloat16* lp = lds + buf * 32768 + h * 8192 + uB;
        async_load16(g, lp);
        async_load16(g + (size_t)64 * ldbt, lp + 4096);
    };
    auto LDA4 = [&](int buf, int mlo) {
        const __hip_bfloat16* p0 = lds + buf * 32768 + ra;
        #pragma unroll
        for (int j = 0; j < 4; ++j) {
            af[j][0] = *(const bf16x8*)(const void*)(p0 + (mlo + j) * 1024 + cx0);
            af[j][1] = *(const bf16x8*)(const void*)(p0 + (mlo + j) * 1024 + cx1);
        }
    };
    auto LDB2 = [&](int buf, int nlo) {
        const __hip_bfloat16* p0 = lds + buf * 32768 + rb;
        #pragma unroll
        for (int n = 0; n < 2; ++n) {
            bfr[nlo + n][0] = *(const bf16x8*)(const void*)(p0 + (nlo + n) * 1024 + cx0);
            bfr[nlo + n][1] = *(const bf16x8*)(const void*)(p0 + (nlo + n) * 1024 + cx1);
        }
    };
    auto MMQ = [&](int mlo, int nlo) {
        __builtin_amdgcn_s_setprio(1);
        #pragma unroll
        for (int j = 0; j < 4; ++j)
            #pragma unroll
            for (int n = 0; n < 2; ++n)
                #pragma unroll
                for (int ks = 0; ks < 2; ++ks)
                    acc[mlo + j][nlo + n] = __builtin_amdgcn_mfma_f32_16x16x32_bf16(
                        af[j][ks], bfr[nlo + n][ks], acc[mlo + j][nlo + n], 0, 0, 0);
        __builtin_amdgcn_s_setprio(0);
    };

    // prologue: tile0 fully (8 loads) + tile1 A0,B0,B1 (A1(1) staged at it0-P1)
    STG_A(0, 0, 0); STG_B(0, 0, 0); STG_B(0, 1, 0); STG_A(0, 1, 0);
    STG_A(1, 0, 1); STG_B(1, 0, 1); STG_B(1, 1, 1);
    VMC(6);                 // tile0's 8 loads drained
    BAR();

    for (int it = 0; it < nit; ++it) {
        const int t0 = 2 * it, t1 = t0 + 1;
        const bool nl = (it + 1 < nit);
        // ---- tile t0 (buf0) ----
        // P1: (m-lo, n-lo); stage buf1 A1 for tile t1 (buf1 A free since prev P7)
        LDA4(0, 0); LDB2(0, 0); STG_A(1, 1, t1);
        BAR(); LGKM0(); MMQ(0, 0); BAR();
        // P2: (m-lo, n-hi)
        LDB2(0, 2);
        BAR(); LGKM0(); MMQ(0, 2); BAR();
        // P3: (m-hi, n-hi); buf0 B free after P2 -> stage B0
        LDA4(0, 4); if (nl) STG_B(0, 0, t0 + 2);
        BAR(); LGKM0(); MMQ(4, 2); BAR();
        // P4: (m-hi, n-lo); buf0 A free after P3 -> stage B1,A0; drain buf1(t1)
        if (nl) { STG_B(0, 1, t0 + 2); STG_A(0, 0, t0 + 2); VMC(6); }
        else    { VMC(0); }
        BAR(); MMQ(4, 0); BAR();
        // ---- tile t1 (buf1) ----
        // P5: stage buf0 A1 (buf0 A free since P3)
        LDA4(1, 0); LDB2(1, 0); if (nl) STG_A(0, 1, t0 + 2);
        BAR(); LGKM0(); MMQ(0, 0); BAR();
        // P6
        LDB2(1, 2);
        BAR(); LGKM0(); MMQ(0, 2); BAR();
        // P7: buf1 B free after P6 -> stage B0
        LDA4(1, 4); if (nl) STG_B(1, 0, t1 + 2);
        BAR(); LGKM0(); MMQ(4, 2); BAR();
        // P8: buf1 A free after P7 -> stage B1,A0; drain buf0(t0+2)
        if (nl) { STG_B(1, 1, t1 + 2); STG_A(1, 0, t1 + 2); VMC(6); }
        BAR(); MMQ(4, 0); BAR();
    }
}

// ---------------------------------------------------------------------------
// Merged launch, 256 blocks (natural dispatch order — no XCD swizzle, R7):
//   0..191   : q = hidden @ WqT (24x8 tiles), bias+RoPE+SCALE -> q_bf
//   192..215 : ckv = hidden @ WkvaT (3x8, N padded 640->768)
//   216..255 : Wkvb transpose (1024 tiles) + TOP half of Wo (1024 tiles):
//              50 MB / (40 CU x 24.6 GB/s) ~ 52 us < 71 us GEMM -> hides.
// ---------------------------------------------------------------------------
__global__ __launch_bounds__(512)
void gemm_q_ckv(const __hip_bfloat16* __restrict__ A,
                const __hip_bfloat16* __restrict__ BtQ,
                const __hip_bfloat16* __restrict__ BtKVA,
                const float* __restrict__ bq,
                const float* __restrict__ bkva,
                const float* __restrict__ cosb, const float* __restrict__ sinb,
                __hip_bfloat16* __restrict__ C,
                __hip_bfloat16* __restrict__ kvlat,
                __hip_bfloat16* __restrict__ kr,
                const float* __restrict__ Wkvb, __hip_bfloat16* __restrict__ WkvbT,
                const float* __restrict__ Wo,   __hip_bfloat16* __restrict__ WoT)
{
    __shared__ __hip_bfloat16 lds[65536];   // 128 KiB
    const int bid = blockIdx.x;
    const int t = threadIdx.x;

    if (bid >= 216) {
        // ---- transpose tail: 40 blocks x ~51 tiles of 64x64, ushort4 stores ----
        float (*tile)[65] = (float (*)[65])(void*)lds;   // 16.6 KB of 128 KB
        const int r   = t >> 4;          // 0..31
        const int c4  = (t & 15) * 4;
        const int tx0 = (t & 15) * 4;
        const int drb = t >> 4;          // 0..31
        for (int id = bid - 216; id < 2048; id += 40) {
            const float* src; __hip_bfloat16* dst; int cols, CX, drows, tid;
            if (id < 1024) { src = Wkvb; dst = WkvbT; cols = KVN;     CX = 128; drows = KV_RANK; tid = id; }
            else           { src = Wo;   dst = WoT;   cols = OUT_HID; CX = 32;  drows = NH * VD; tid = id - 1024; }
            const int bx = tid % CX, by = tid / CX;
            const int r0 = by * 64, c0 = bx * 64;
            #pragma unroll
            for (int i = 0; i < 2; ++i) {
                const int rr = r + i * 32;
                float4 v = *(const float4*)&src[(size_t)(r0 + rr) * cols + c0 + c4];
                tile[rr][c4 + 0] = v.x;
                tile[rr][c4 + 1] = v.y;
                tile[rr][c4 + 2] = v.z;
                tile[rr][c4 + 3] = v.w;
            }
            __syncthreads();
            #pragma unroll
            for (int i = 0; i < 2; ++i) {
                const int dr = drb + i * 32;
                __hip_bfloat16 b0 = __float2bfloat16(tile[tx0 + 0][dr]);
                __hip_bfloat16 b1 = __float2bfloat16(tile[tx0 + 1][dr]);
                __hip_bfloat16 b2 = __float2bfloat16(tile[tx0 + 2][dr]);
                __hip_bfloat16 b3 = __float2bfloat16(tile[tx0 + 3][dr]);
                ushort4 pk;
                pk.x = *(unsigned short*)&b0; pk.y = *(unsigned short*)&b1;
                pk.z = *(unsigned short*)&b2; pk.w = *(unsigned short*)&b3;
                *(ushort4*)&dst[(size_t)(c0 + dr) * drows + r0 + tx0] = pk;
            }
            __syncthreads();
        }
        return;
    }

    const bool is_q = (bid < 192);
    const int m0 = (is_q ? (bid / 24) : ((bid - 192) / 3)) * 256;
    const int n0 = (is_q ? (bid % 24) : ((bid - 192) % 3)) * 256;

    f32x4 acc[8][4];
    #pragma unroll
    for (int mi = 0; mi < 8; ++mi)
        #pragma unroll
        for (int ni = 0; ni < 4; ++ni) acc[mi][ni] = (f32x4){0.f, 0.f, 0.f, 0.f};

    gemm256_core(A, HID_DIM, is_q ? BtQ : BtKVA, HID_DIM, m0, n0, 0,
                 HID_DIM / 128, lds, acc);

    const int w = t >> 6, L = t & 63;
    const int lane15 = L & 15, quad = L >> 4;
    const int wr = w >> 2, wc = w & 3;
    const int ns = n0 + wc * 64;

    if (is_q) {
        const bool do_rope = ((ns % 192) == 128);   // 64-strip == rope dims of a head
        float bv[4];
        #pragma unroll
        for (int ni = 0; ni < 4; ++ni) bv[ni] = bq[ns + ni * 16 + lane15];

        #pragma unroll
        for (int mi = 0; mi < 8; ++mi) {
            const int rbase = m0 + wr * 128 + mi * 16 + quad * 4;
            float vv[4][4];
            #pragma unroll
            for (int ni = 0; ni < 4; ++ni)
                #pragma unroll
                for (int p = 0; p < 4; ++p) vv[ni][p] = acc[mi][ni][p] + bv[ni];
            if (do_rope) {
                #pragma unroll
                for (int ni = 0; ni < 2; ++ni) {
                    const int dd = ni * 16 + lane15;
                    #pragma unroll
                    for (int p = 0; p < 4; ++p) {
                        const int srow = rbase + p;
                        const float c0 = cosb[srow * ROPE_D + dd];
                        const float c1 = cosb[srow * ROPE_D + dd + 32];
                        const float s0 = sinb[srow * ROPE_D + dd];
                        const float s1 = sinb[srow * ROPE_D + dd + 32];
                        const float x0 = vv[ni][p], x1 = vv[ni + 2][p];
                        vv[ni][p]     = x0 * c0 - x1 * s0;
                        vv[ni + 2][p] = x1 * c1 + x0 * s1;
                    }
                }
            }
            #pragma unroll
            for (int ni = 0; ni < 4; ++ni) {
                const int c = ns + ni * 16 + lane15;
                #pragma unroll
                for (int p = 0; p < 4; ++p)
                    C[(size_t)(rbase + p) * NQK + c] = __float2bfloat16(vv[ni][p] * ATT_SCALE);
            }
        }
    } else if (ns < KV_RANK) {
        // kvlat strips (all 64 cols < 512)
        float bv[4];
        #pragma unroll
        for (int ni = 0; ni < 4; ++ni) bv[ni] = bkva[ns + ni * 16 + lane15];
        #pragma unroll
        for (int mi = 0; mi < 8; ++mi) {
            const int s = m0 + wr * 128 + mi * 16 + quad * 4;
            #pragma unroll
            for (int ni = 0; ni < 4; ++ni) {
                const int c = ns + ni * 16 + lane15;
                #pragma unroll
                for (int p = 0; p < 4; ++p)
                    kvlat[(size_t)(s + p) * KV_RANK + c] =
                        __float2bfloat16(acc[mi][ni][p] + bv[ni]);
            }
        }
    } else if (ns == KV_RANK) {
        // k-RoPE strip: cols 512..575; pairs (512+d, 544+d), d = ni*16+lane15
        #pragma unroll
        for (int mi = 0; mi < 8; ++mi) {
            const int sb = m0 + wr * 128 + mi * 16 + quad * 4;
            #pragma unroll
            for (int ni = 0; ni < 2; ++ni) {
                const int d = ni * 16 + lane15;
                const float ba = bkva[512 + d], bb = bkva[544 + d];
                #pragma unroll
                for (int p = 0; p < 4; ++p) {
                    const int s = sb + p;
                    const float a = acc[mi][ni][p] + ba;
                    const float b = acc[mi][ni + 2][p] + bb;
                    const float c0 = cosb[s * ROPE_D + d], c1 = cosb[s * ROPE_D + d + 32];
                    const float s0 = sinb[s * ROPE_D + d], s1 = sinb[s * ROPE_D + d + 32];
                    kr[(size_t)s * ROPE_D + d]      = __float2bfloat16(a * c0 - b * s0);
                    kr[(size_t)s * ROPE_D + d + 32] = __float2bfloat16(b * c1 + a * s1);
                }
            }
        }
    }
    // ns >= 576: padding strips, no store
}

// ---------------------------------------------------------------------------
// kv up-proj GEMM, 256x256 8-phase core; split epilogue kn + transposed V.
// ---------------------------------------------------------------------------
__global__ __launch_bounds__(512)
void gemm_kv256(const __hip_bfloat16* __restrict__ A,
                const __hip_bfloat16* __restrict__ Bt,
                __hip_bfloat16* __restrict__ kn,
                __hip_bfloat16* __restrict__ vt)
{
    __shared__ __hip_bfloat16 lds[65536];
    const int m0 = blockIdx.y * 256, n0 = blockIdx.x * 256;
    f32x4 acc[8][4];
    #pragma unroll
    for (int mi = 0; mi < 8; ++mi)
        #pragma unroll
        for (int ni = 0; ni < 4; ++ni) acc[mi][ni] = (f32x4){0.f, 0.f, 0.f, 0.f};

    gemm256_core(A, KV_RANK, Bt, KV_RANK, m0, n0, 0, KV_RANK / 128, lds, acc);

    const int t = threadIdx.x;
    const int w = t >> 6, L = t & 63;
    const int lane15 = L & 15, quad = L >> 4;
    const int wr = w >> 2, wc = w & 3;
    const int ns = n0 + wc * 64;

    #pragma unroll
    for (int mi = 0; mi < 8; ++mi) {
        const int rbase = m0 + wr * 128 + mi * 16 + quad * 4;
        #pragma unroll
        for (int ni = 0; ni < 4; ++ni) {
            const int c = ns + ni * 16 + lane15;
            const int h = c >> 8, d = c & 255;
            if (d < NOPE) {
                #pragma unroll
                for (int p = 0; p < 4; ++p)
                    kn[(size_t)(rbase + p) * KNW + h * NOPE + d] = __float2bfloat16(acc[mi][ni][p]);
            } else {
                ushort4 pk;
                __hip_bfloat16 b0 = __float2bfloat16(acc[mi][ni][0]);
                __hip_bfloat16 b1 = __float2bfloat16(acc[mi][ni][1]);
                __hip_bfloat16 b2 = __float2bfloat16(acc[mi][ni][2]);
                __hip_bfloat16 b3 = __float2bfloat16(acc[mi][ni][3]);
                pk.x = *(unsigned short*)&b0; pk.y = *(unsigned short*)&b1;
                pk.z = *(unsigned short*)&b2; pk.w = *(unsigned short*)&b3;
                *(ushort4*)(vt + (size_t)(h * VD + (d - NOPE)) * S_LEN + rbase) = pk;
            }
        }
    }
}

// ---------------------------------------------------------------------------
// Split-K GEMM, 256x256 8-phase core, BF16 partial epilogue (R9: halves the
// partial traffic; rounding adds <=~0.006 to absmax, within threshold).
// ---------------------------------------------------------------------------
__global__ __launch_bounds__(512)
void gemm_partial256(const __hip_bfloat16* __restrict__ A, int lda,
                     const __hip_bfloat16* __restrict__ Bt, int ldbt,
                     __hip_bfloat16* __restrict__ P, int ldp, size_t zstride, int KL)
{
    __shared__ __hip_bfloat16 lds[65536];
    const int m0 = blockIdx.y * 256, n0 = blockIdx.x * 256;
    const int z  = blockIdx.z;
    f32x4 acc[8][4];
    #pragma unroll
    for (int mi = 0; mi < 8; ++mi)
        #pragma unroll
        for (int ni = 0; ni < 4; ++ni) acc[mi][ni] = (f32x4){0.f, 0.f, 0.f, 0.f};

    gemm256_core(A, lda, Bt, ldbt, m0, n0, z * KL, KL / 128, lds, acc);

    const int t = threadIdx.x;
    const int w = t >> 6, L = t & 63;
    const int lane15 = L & 15, quad = L >> 4;
    const int wr = w >> 2, wc = w & 3;
    __hip_bfloat16* Pz = P + (size_t)z * zstride;

    #pragma unroll
    for (int mi = 0; mi < 8; ++mi) {
        const int rbase = m0 + wr * 128 + mi * 16 + quad * 4;
        #pragma unroll
        for (int ni = 0; ni < 4; ++ni) {
            const int c = n0 + wc * 64 + ni * 16 + lane15;
            #pragma unroll
            for (int p = 0; p < 4; ++p)
                Pz[(size_t)(rbase + p) * ldp + c] = __float2bfloat16(acc[mi][ni][p]);
        }
    }
}

// ---------------------------------------------------------------------------
// Wo reduce: out = P0 + P1 + P2 + P3 + bo  (bf16 partials in, fp32 out).
// Thread handles 4 out elems: 4x ushort4 loads + float4 store.
// ---------------------------------------------------------------------------
__device__ __forceinline__ float b2f(unsigned short u) {
    __hip_bfloat16 h = *(__hip_bfloat16*)&u;
    return __bfloat162float(h);
}

__global__ __launch_bounds__(256)
void wo_reduce4(const __hip_bfloat16* __restrict__ P, const float* __restrict__ bo,
                float* __restrict__ out)
{
    const size_t i = (size_t)blockIdx.x * 256 + threadIdx.x;  // 4-elem index
    const size_t zs = (size_t)S_LEN * OUT_HID;
    ushort4 a = ((const ushort4*)P)[i];
    ushort4 b = ((const ushort4*)(P + zs))[i];
    ushort4 c = ((const ushort4*)(P + 2 * zs))[i];
    ushort4 d = ((const ushort4*)(P + 3 * zs))[i];
    const int col = (int)((i * 4) & (OUT_HID - 1));
    float4 bb = *(const float4*)(bo + col);
    float4 o;
    o.x = b2f(a.x) + b2f(b.x) + b2f(c.x) + b2f(d.x) + bb.x;
    o.y = b2f(a.y) + b2f(b.y) + b2f(c.y) + b2f(d.y) + bb.y;
    o.z = b2f(a.z) + b2f(b.z) + b2f(c.z) + b2f(d.z) + bb.z;
    o.w = b2f(a.w) + b2f(b.w) + b2f(c.w) + b2f(d.w) + bb.w;
    ((float4*)out)[i] = o;
}

// ---------------------------------------------------------------------------
// MFMA sliding-window attention with sink. T14 async-stage split (R8):
// K/V chunk loads issued into registers one chunk early; ds_write after the
// barrier. Same barrier structure & buffers as the verified R2 version.
// ---------------------------------------------------------------------------
#define SS 170     // fp32 S stride
#define SP 168     // bf16 P stride
#define KSTR 200   // staged K row stride (bf16), 400B, 16B-aligned
#define VSTR 40    // staged V row stride (bf16), 80B, 16B-aligned

__global__ __launch_bounds__(256)
void attn_mfma2(const __hip_bfloat16* __restrict__ q,
                const __hip_bfloat16* __restrict__ kn,
                const __hip_bfloat16* __restrict__ kr,
                const __hip_bfloat16* __restrict__ vt,
                const float* __restrict__ sinks,
                __hip_bfloat16* __restrict__ out)
{
    __shared__ float lds_s[32 * SS];
    __shared__ __hip_bfloat16 lds_p[32 * SP];
    __shared__ __hip_bfloat16 lds_kv[32 * KSTR];   // also used as [128][VSTR]

    const int h  = blockIdx.y;
    const int q0 = blockIdx.x * 32;
    const int t  = threadIdx.x;
    const int w  = t >> 6;
    const int L  = t & 63;
    const int lane15 = L & 15, quad = L >> 4;
    const int wm = (w & 1) * 16;
    const int wn = (w >> 1) * 16;

    int lo = q0 - SW + 1; if (lo < 0) lo = 0;
    const int cb = lo & ~31;
    const int nc = ((q0 - cb) >> 5) + 1;    // 1..5

    // T14 staging registers + helpers
    bf16x8 kreg[3];
    auto issueK = [&](int c0) {
        #pragma unroll
        for (int i = 0; i < 3; ++i) {
            const int e = t + i * 256;
            const int row = e / 24, slot = e % 24;
            const int j = c0 + row;
            const __hip_bfloat16* g = (slot < 16)
                ? kn + (size_t)j * KNW + h * NOPE + slot * 8
                : kr + (size_t)j * ROPE_D + (slot - 16) * 8;
            kreg[i] = *(const bf16x8*)(const void*)g;
        }
    };
    auto writeK = [&]() {
        #pragma unroll
        for (int i = 0; i < 3; ++i) {
            const int e = t + i * 256;
            const int row = e / 24, slot = e % 24;
            *(bf16x8*)(void*)(lds_kv + row * KSTR + slot * 8) = kreg[i];
        }
    };
    bf16x8 vreg[2];
    auto issueV = [&](int c0) {
        #pragma unroll
        for (int i = 0; i < 2; ++i) {
            const int e = t + i * 256;
            const int row = e >> 2, slot = e & 3;
            vreg[i] = *(const bf16x8*)(const void*)(
                vt + (size_t)(h * VD + row) * S_LEN + c0 + slot * 8);
        }
    };
    auto writeV = [&]() {
        #pragma unroll
        for (int i = 0; i < 2; ++i) {
            const int e = t + i * 256;
            const int row = e >> 2, slot = e & 3;
            *(bf16x8*)(void*)(lds_kv + row * VSTR + slot * 8) = vreg[i];
        }
    };

    bf16x8 qf[6];
    {
        const __hip_bfloat16* qrow = q + (size_t)(q0 + wm + lane15) * NQK + h * QKD;
        #pragma unroll
        for (int kk = 0; kk < 6; ++kk)
            qf[kk] = *(const bf16x8*)(const void*)(qrow + kk * 32 + quad * 8);
    }

    // ---- QK^T per chunk (K loads issued one chunk early) ----
    issueK(cb);
    for (int cc = 0; cc < nc; ++cc) {
        const int c0 = cb + cc * 32;
        __syncthreads();                 // previous chunk's LDS fully consumed
        writeK();
        if (cc + 1 < nc) issueK(cb + (cc + 1) * 32);   // fly under barrier+MFMA
        __syncthreads();

        f32x4 s = (f32x4){0.f, 0.f, 0.f, 0.f};
        #pragma unroll
        for (int kk = 0; kk < 6; ++kk) {
            bf16x8 bf = *(const bf16x8*)(const void*)(lds_kv + (wn + lane15) * KSTR + kk * 32 + quad * 8);
            s = __builtin_amdgcn_mfma_f32_16x16x32_bf16(qf[kk], bf, s, 0, 0, 0);
        }
        const int j = c0 + wn + lane15;
        #pragma unroll
        for (int p = 0; p < 4; ++p) {
            const int i = q0 + wm + quad * 4 + p;
            const bool ok = (j <= i) && (i - j < SW);
            lds_s[(wm + quad * 4 + p) * SS + cc * 32 + wn + lane15] = ok ? s[p] : NEG_INF;
        }
    }
    __syncthreads();

    issueV(cb);                          // V chunk 0 loads fly under softmax

    {
        const int r = t >> 3, g = t & 7;
        const int ncols = nc * 32;
        const float sink = sinks[h];
        float mx = sink;
        for (int c = g; c < ncols; c += 8)
            mx = fmaxf(mx, lds_s[r * SS + c]);
        #pragma unroll
        for (int off = 1; off < 8; off <<= 1)
            mx = fmaxf(mx, __shfl_xor(mx, off));
        float sum = 0.f;
        for (int c = g; c < ncols; c += 8) {
            float e = __expf(lds_s[r * SS + c] - mx);
            lds_s[r * SS + c] = e;
            sum += e;
        }
        #pragma unroll
        for (int off = 1; off < 8; off <<= 1)
            sum += __shfl_xor(sum, off);
        const float inv = 1.0f / (sum + __expf(sink - mx));
        for (int c = g; c < ncols; c += 8)
            lds_p[r * SP + c] = __float2bfloat16(lds_s[r * SS + c] * inv);
    }

    // ---- PV per chunk (V loads issued one chunk early) ----
    f32x4 oacc[4];
    #pragma unroll
    for (int ni = 0; ni < 4; ++ni) oacc[ni] = (f32x4){0.f, 0.f, 0.f, 0.f};

    for (int cc = 0; cc < nc; ++cc) {
        __syncthreads();                 // softmax done (cc==0) / prev PV done
        writeV();
        if (cc + 1 < nc) issueV(cb + (cc + 1) * 32);
        __syncthreads();

        bf16x8 ap = *(const bf16x8*)(const void*)(lds_p + (wm + lane15) * SP + cc * 32 + quad * 8);
        #pragma unroll
        for (int ni = 0; ni < 4; ++ni) {
            bf16x8 bv = *(const bf16x8*)(const void*)(lds_kv + ((w >> 1) * 64 + ni * 16 + lane15) * VSTR + quad * 8);
            oacc[ni] = __builtin_amdgcn_mfma_f32_16x16x32_bf16(ap, bv, oacc[ni], 0, 0, 0);
        }
    }

    #pragma unroll
    for (int ni = 0; ni < 4; ++ni) {
        const int col = h * VD + (w >> 1) * 64 + ni * 16 + lane15;
        #pragma unroll
        for (int p = 0; p < 4; ++p) {
            const int row = q0 + wm + quad * 4 + p;
            out[(size_t)row * (NH * VD) + col] = __float2bfloat16(oacc[ni][p]);
        }
    }
}

// ---------------------------------------------------------------------------
extern "C" void kernel_launch(void* const* d_in, const int* in_sizes, int n_in,
                              void* d_out, int out_size, void* d_ws, size_t ws_size,
                              hipStream_t stream) {
    const float* hidden = (const float*)d_in[0];
    const float* cosb   = (const float*)d_in[1];
    const float* sinb   = (const float*)d_in[2];
    const float* Wq     = (const float*)d_in[3];
    const float* bq     = (const float*)d_in[4];
    const float* Wkva   = (const float*)d_in[5];
    const float* bkva   = (const float*)d_in[6];
    const float* Wkvb   = (const float*)d_in[7];
    const float* Wo     = (const float*)d_in[8];
    const float* bo     = (const float*)d_in[9];
    const float* sinks  = (const float*)d_in[10];
    float* out = (float*)d_out;

    // workspace, 139.0 MB. Alias:
    //   WoP (33.6 MB bf16 partials) <- q_bf (25.2 MB) + hid_bf head, dead after attn
    uint8_t* p = (uint8_t*)d_ws;
    __hip_bfloat16* attn_bf = (__hip_bfloat16*)p; p += (size_t)S_LEN * NH * VD * 2;   // 16.78 MB
    __hip_bfloat16* WoT     = (__hip_bfloat16*)p; p += (size_t)OUT_HID * (NH*VD) * 2; // 16.78 MB
    __hip_bfloat16* q_bf    = (__hip_bfloat16*)p; p += (size_t)S_LEN * NQK * 2;       // 25.17 MB
    __hip_bfloat16* hid_bf  = (__hip_bfloat16*)p; p += (size_t)S_LEN * HID_DIM * 2;   //  8.39 MB
    __hip_bfloat16* WqT     = (__hip_bfloat16*)p; p += (size_t)NQK * HID_DIM * 2;     // 25.17 MB
    __hip_bfloat16* WkvaT   = (__hip_bfloat16*)p; p += (size_t)640 * HID_DIM * 2;     //  2.62 MB
    __hip_bfloat16* WkvbT   = (__hip_bfloat16*)p; p += (size_t)KVN * KV_RANK * 2;     //  8.39 MB
    __hip_bfloat16* kn_bf   = (__hip_bfloat16*)p; p += (size_t)S_LEN * KNW * 2;       // 16.78 MB
    __hip_bfloat16* vt_bf   = (__hip_bfloat16*)p; p += (size_t)S_LEN * NH * VD * 2;   // 16.78 MB
    __hip_bfloat16* kr_bf   = (__hip_bfloat16*)p; p += (size_t)S_LEN * ROPE_D * 2;    //  0.26 MB
    __hip_bfloat16* kvlat   = (__hip_bfloat16*)p; p += (size_t)S_LEN * KV_RANK * 2;   //  2.10 MB
    __hip_bfloat16* WoP = q_bf;    // after attn (33.6 MB bf16 < q_bf+hid_bf)

    // 1. conversions: hidden (4096) + Wq (3072) + Wkva (288) + Wo-bottom (1024)
    prep<<<8480, 256, 0, stream>>>(hidden, hid_bf, Wq, WqT, Wkva, WkvaT, Wo, WoT);

    // 2. merged: q-proj (192) + ckv-proj (24) + Wkvb & Wo-top transposes (40)
    gemm_q_ckv<<<256, 512, 0, stream>>>(
        hid_bf, WqT, WkvaT, bq, bkva, cosb, sinb, q_bf, kvlat, kr_bf,
        Wkvb, WkvbT, Wo, WoT);

    // 3. kv up-proj: kn + transposed V  [256^2 8-phase, 256 blocks]
    gemm_kv256<<<dim3(KVN / 256, S_LEN / 256), 512, 0, stream>>>(
        kvlat, WkvbT, kn_bf, vt_bf);

    // 4. attention (MFMA, LDS-staged K/V, T14 async staging)
    attn_mfma2<<<dim3(S_LEN / 32, NH), 256, 0, stream>>>(
        q_bf, kn_bf, kr_bf, vt_bf, sinks, attn_bf);

    // 5. Wo partials: split-K x4, bf16 partials (256 blocks, 256^2 8-phase)
    gemm_partial256<<<dim3(OUT_HID / 256, S_LEN / 256, 4), 512, 0, stream>>>(
        attn_bf, NH * VD, WoT, NH * VD, WoP, OUT_HID, (size_t)S_LEN * OUT_HID, 1024);

    // 6. out = P0+P1+P2+P3 + bo
    wo_reduce4<<<(S_LEN * OUT_HID / 4) / 256, 256, 0, stream>>>(WoP, bo, out);
}

// Round 11
// 333.955 us; speedup vs baseline: 1.0021x; 1.0021x over previous
//
#include <hip/hip_runtime.h>
#include <hip/hip_bf16.h>
#include <math.h>

#define S_LEN 2048
#define HID_DIM 2048
#define NH 32
#define NOPE 128
#define ROPE_D 64
#define QKD 192           // NOPE + ROPE
#define VD 128
#define KV_RANK 512
#define SW 128
#define NQK (NH*QKD)      // 6144
#define CKV_N (KV_RANK+ROPE_D) // 576
#define KVN (NH*(NOPE+VD))     // 8192
#define KNW (NH*NOPE)          // 4096
#define OUT_HID 2048
#define ATT_SCALE 0.07216878364870323f  // 192^-0.5
#define NEG_INF (-1e30f)

typedef __bf16 bf16x8 __attribute__((ext_vector_type(8)));
typedef float  f32x4  __attribute__((ext_vector_type(4)));

// ---------------------------------------------------------------------------
// async global->LDS, 16B per lane. LDS dest = wave-uniform base + lane*16.
// ---------------------------------------------------------------------------
__device__ __forceinline__ void async_load16(const void* gp, void* lp) {
    __builtin_amdgcn_global_load_lds(
        (const __attribute__((address_space(1))) void*)gp,
        (__attribute__((address_space(3))) void*)lp, 16, 0, 0);
}

// ---------------------------------------------------------------------------
// prep: hidden cvt + Wq/Wkva/Wo transposes. float4 reads (R4), ushort4
// transpose stores (R7). Wkvb transpose rides in gemm_q_ckv's idle tail
// (R10 lesson: tail budget is COMBINED r+w traffic ~71 MB; Wkvb=37.5 fits,
// +Wo-half=75 did not).
// ---------------------------------------------------------------------------
__global__ __launch_bounds__(256)
void prep(const float* __restrict__ hidden, __hip_bfloat16* __restrict__ hid_bf,
          const float* __restrict__ Wq,   __hip_bfloat16* __restrict__ WqT,
          const float* __restrict__ Wkva, __hip_bfloat16* __restrict__ WkvaT,
          const float* __restrict__ Wo,   __hip_bfloat16* __restrict__ WoT)
{
    __shared__ float tile[64][65];
    int b = blockIdx.x;
    const int t = threadIdx.x;

    if (b < 4096) {
        int i = b * 256 + t;
        float4 v = ((const float4*)hidden)[i];
        hid_bf[i * 4 + 0] = __float2bfloat16(v.x);
        hid_bf[i * 4 + 1] = __float2bfloat16(v.y);
        hid_bf[i * 4 + 2] = __float2bfloat16(v.z);
        hid_bf[i * 4 + 3] = __float2bfloat16(v.w);
        return;
    }
    b -= 4096;
    const float* src; __hip_bfloat16* dst; int rows, cols, CX;
    if (b < 3072)               { src = Wq;   dst = WqT;   rows = 2048; cols = 6144; CX = 96; }
    else if ((b -= 3072) < 288) { src = Wkva; dst = WkvaT; rows = 2048; cols = 576;  CX = 9;  }
    else { b -= 288;              src = Wo;   dst = WoT;   rows = 4096; cols = 2048; CX = 32; }

    const int bx = b % CX, by = b / CX;
    const int r0 = by * 64, c0 = bx * 64;

    // read: float4 per thread, 4 row-groups of 16 lanes x 256B contiguous
    {
        const int r  = t >> 4;          // 0..15
        const int c4 = (t & 15) * 4;    // 0,4,..,60
        #pragma unroll
        for (int i = 0; i < 4; ++i) {
            const int rr = r + i * 16;
            float4 v = *(const float4*)&src[(size_t)(r0 + rr) * cols + c0 + c4];
            tile[rr][c4 + 0] = v.x;
            tile[rr][c4 + 1] = v.y;
            tile[rr][c4 + 2] = v.z;
            tile[rr][c4 + 3] = v.w;
        }
    }
    __syncthreads();
    // write: ushort4 per thread (4 consecutive dst cols = src rows, fixed dr)
    {
        const int tx0 = (t & 15) * 4;   // src-row group -> dst cols
        const int drb = t >> 4;         // 0..15
        #pragma unroll
        for (int i = 0; i < 4; ++i) {
            const int dr = drb + i * 16;            // src col = dst row
            __hip_bfloat16 b0 = __float2bfloat16(tile[tx0 + 0][dr]);
            __hip_bfloat16 b1 = __float2bfloat16(tile[tx0 + 1][dr]);
            __hip_bfloat16 b2 = __float2bfloat16(tile[tx0 + 2][dr]);
            __hip_bfloat16 b3 = __float2bfloat16(tile[tx0 + 3][dr]);
            ushort4 pk;
            pk.x = *(unsigned short*)&b0; pk.y = *(unsigned short*)&b1;
            pk.z = *(unsigned short*)&b2; pk.w = *(unsigned short*)&b3;
            *(ushort4*)&dst[(size_t)(c0 + dr) * rows + r0 + tx0] = pk;
        }
    }
}

// ---------------------------------------------------------------------------
// 256x256 8-phase bf16 GEMM core (T2 swizzle + T3/T4 counted vmcnt + T5).
//   BM=BN=256, BK=64, 8 waves (2M x 4N), per-wave output 128x64.
//   LDS 128 KiB: 2 buffers x (A 256x64 + B 256x64) bf16.
//   Bank swizzle: physical 16B-chunk = logical_chunk ^ (row & 7), applied on
//   the global SOURCE (stage) and the ds_read address; LDS dest linear.
//   Liveness: B half-tiles read at phases 1-2, A at phases 1,3 =>
//     P3: B0 | P4: B1,A0 + vmcnt(6) | P5: A1  (mirrored P7/P8/P1').
//   R4 lesson: drain is STG -> VMC(6) -> BAR -> MMQ (moving VMC after MMQ
//   regressed 20%). R7 lesson: XCD swizzle HURTS here (fully-resident grid:
//   natural round-robin keeps 3 B-panels/XCD L2-resident; swizzle thrashed).
// ---------------------------------------------------------------------------
#define BAR()   __builtin_amdgcn_s_barrier()
#define LGKM0() asm volatile("s_waitcnt lgkmcnt(0)" ::: "memory")
#define VMC(n)  asm volatile("s_waitcnt vmcnt(" #n ")" ::: "memory")

__device__ __forceinline__ void gemm256_core(
    const __hip_bfloat16* __restrict__ A, int lda,
    const __hip_bfloat16* __restrict__ Bt, int ldbt,
    int m0, int n0, int kbeg, int nit,
    __hip_bfloat16* lds, f32x4 (&acc)[8][4])
{
    const int t = threadIdx.x;
    const int w = t >> 6, L = t & 63;
    const int lane15 = L & 15, quad = L >> 4;
    const int wr = w >> 2, wc = w & 3;

    // staging addressing: wave w, load i covers physical rows w*8+i*64 ..+8
    const int prw = w * 8 + (L >> 3);                 // row, load i=0
    const int c8  = ((L & 7) ^ ((L >> 3) & 7)) * 8;   // inverse-swizzled k-chunk (elems)
    const __hip_bfloat16* gA = A  + (size_t)(m0 + prw) * lda  + kbeg + c8;
    const __hip_bfloat16* gB = Bt + (size_t)(n0 + prw) * ldbt + kbeg + c8;
    const int uA = w * 512;              // elem offset; +buf*32768 +h*8192 (+4096 i=1)
    const int uB = 16384 + w * 512;

    // read addressing (swizzled chunk per lane; row%8 == lane15%8 always)
    const int cx0 = ((quad)     ^ (L & 7)) * 8;       // ks=0
    const int cx1 = ((4 + quad) ^ (L & 7)) * 8;       // ks=1
    const int ra  = wr * 8192 + lane15 * 64;                                  // A
    const int rb  = 16384 + (wc >> 1) * 8192 + (wc & 1) * 4096 + lane15 * 64; // B

    bf16x8 af[4][2], bfr[4][2];

    auto STG_A = [&](int buf, int h, int kt) {
        const __hip_bfloat16* g = gA + (size_t)h * 128 * lda + kt * 64;
        __hip_bfloat16* lp = lds + buf * 32768 + h * 8192 + uA;
        async_load16(g, lp);
        async_load16(g + (size_t)64 * lda, lp + 4096);
    };
    auto STG_B = [&](int buf, int h, int kt) {
        const __hip_bfloat16* g = gB + (size_t)h * 128 * ldbt + kt * 64;
        __hip_bfloat16* lp = lds + buf * 32768 + h * 8192 + uB;
        async_load16(g, lp);
        async_load16(g + (size_t)64 * ldbt, lp + 4096);
    };
    auto LDA4 = [&](int buf, int mlo) {
        const __hip_bfloat16* p0 = lds + buf * 32768 + ra;
        #pragma unroll
        for (int j = 0; j < 4; ++j) {
            af[j][0] = *(const bf16x8*)(const void*)(p0 + (mlo + j) * 1024 + cx0);
            af[j][1] = *(const bf16x8*)(const void*)(p0 + (mlo + j) * 1024 + cx1);
        }
    };
    auto LDB2 = [&](int buf, int nlo) {
        const __hip_bfloat16* p0 = lds + buf * 32768 + rb;
        #pragma unroll
        for (int n = 0; n < 2; ++n) {
            bfr[nlo + n][0] = *(const bf16x8*)(const void*)(p0 + (nlo + n) * 1024 + cx0);
            bfr[nlo + n][1] = *(const bf16x8*)(const void*)(p0 + (nlo + n) * 1024 + cx1);
        }
    };
    auto MMQ = [&](int mlo, int nlo) {
        __builtin_amdgcn_s_setprio(1);
        #pragma unroll
        for (int j = 0; j < 4; ++j)
            #pragma unroll
            for (int n = 0; n < 2; ++n)
                #pragma unroll
                for (int ks = 0; ks < 2; ++ks)
                    acc[mlo + j][nlo + n] = __builtin_amdgcn_mfma_f32_16x16x32_bf16(
                        af[j][ks], bfr[nlo + n][ks], acc[mlo + j][nlo + n], 0, 0, 0);
        __builtin_amdgcn_s_setprio(0);
    };

    // prologue: tile0 fully (8 loads) + tile1 A0,B0,B1 (A1(1) staged at it0-P1)
    STG_A(0, 0, 0); STG_B(0, 0, 0); STG_B(0, 1, 0); STG_A(0, 1, 0);
    STG_A(1, 0, 1); STG_B(1, 0, 1); STG_B(1, 1, 1);
    VMC(6);                 // tile0's 8 loads drained
    BAR();

    for (int it = 0; it < nit; ++it) {
        const int t0 = 2 * it, t1 = t0 + 1;
        const bool nl = (it + 1 < nit);
        // ---- tile t0 (buf0) ----
        // P1: (m-lo, n-lo); stage buf1 A1 for tile t1 (buf1 A free since prev P7)
        LDA4(0, 0); LDB2(0, 0); STG_A(1, 1, t1);
        BAR(); LGKM0(); MMQ(0, 0); BAR();
        // P2: (m-lo, n-hi)
        LDB2(0, 2);
        BAR(); LGKM0(); MMQ(0, 2); BAR();
        // P3: (m-hi, n-hi); buf0 B free after P2 -> stage B0
        LDA4(0, 4); if (nl) STG_B(0, 0, t0 + 2);
        BAR(); LGKM0(); MMQ(4, 2); BAR();
        // P4: (m-hi, n-lo); buf0 A free after P3 -> stage B1,A0; drain buf1(t1)
        if (nl) { STG_B(0, 1, t0 + 2); STG_A(0, 0, t0 + 2); VMC(6); }
        else    { VMC(0); }
        BAR(); MMQ(4, 0); BAR();
        // ---- tile t1 (buf1) ----
        // P5: stage buf0 A1 (buf0 A free since P3)
        LDA4(1, 0); LDB2(1, 0); if (nl) STG_A(0, 1, t0 + 2);
        BAR(); LGKM0(); MMQ(0, 0); BAR();
        // P6
        LDB2(1, 2);
        BAR(); LGKM0(); MMQ(0, 2); BAR();
        // P7: buf1 B free after P6 -> stage B0
        LDA4(1, 4); if (nl) STG_B(1, 0, t1 + 2);
        BAR(); LGKM0(); MMQ(4, 2); BAR();
        // P8: buf1 A free after P7 -> stage B1,A0; drain buf0(t0+2)
        if (nl) { STG_B(1, 1, t1 + 2); STG_A(1, 0, t1 + 2); VMC(6); }
        BAR(); MMQ(4, 0); BAR();
    }
}

// ---------------------------------------------------------------------------
// Merged launch, 256 blocks (natural dispatch order — no XCD swizzle, R7):
//   0..191   : q = hidden @ WqT (24x8 tiles), bias+RoPE+SCALE -> q_bf
//   192..215 : ckv = hidden @ WkvaT (3x8, N padded 640->768)
//   216..255 : Wkvb transpose ONLY (37.5 MB combined r+w ~ 37 us < 71 us
//              GEMM -> hides; R10: +Wo-half = 75 MB did NOT hide)
// ---------------------------------------------------------------------------
__global__ __launch_bounds__(512)
void gemm_q_ckv(const __hip_bfloat16* __restrict__ A,
                const __hip_bfloat16* __restrict__ BtQ,
                const __hip_bfloat16* __restrict__ BtKVA,
                const float* __restrict__ bq,
                const float* __restrict__ bkva,
                const float* __restrict__ cosb, const float* __restrict__ sinb,
                __hip_bfloat16* __restrict__ C,
                __hip_bfloat16* __restrict__ kvlat,
                __hip_bfloat16* __restrict__ kr,
                const float* __restrict__ Wkvb, __hip_bfloat16* __restrict__ WkvbT)
{
    __shared__ __hip_bfloat16 lds[65536];   // 128 KiB
    const int bid = blockIdx.x;
    const int t = threadIdx.x;

    if (bid >= 216) {
        // ---- Wkvb transpose: 40 blocks x ~26 tiles of 64x64, ushort4 stores ----
        float (*tile)[65] = (float (*)[65])(void*)lds;   // 16.6 KB of 128 KB
        const int r   = t >> 4;          // 0..31
        const int c4  = (t & 15) * 4;
        const int tx0 = (t & 15) * 4;
        const int drb = t >> 4;          // 0..31
        for (int id = bid - 216; id < 1024; id += 40) {
            const int bx = id & 127, by = id >> 7;      // CX=128 (8192/64)
            const int r0 = by * 64, c0 = bx * 64;
            #pragma unroll
            for (int i = 0; i < 2; ++i) {
                const int rr = r + i * 32;
                float4 v = *(const float4*)&Wkvb[(size_t)(r0 + rr) * KVN + c0 + c4];
                tile[rr][c4 + 0] = v.x;
                tile[rr][c4 + 1] = v.y;
                tile[rr][c4 + 2] = v.z;
                tile[rr][c4 + 3] = v.w;
            }
            __syncthreads();
            #pragma unroll
            for (int i = 0; i < 2; ++i) {
                const int dr = drb + i * 32;
                __hip_bfloat16 b0 = __float2bfloat16(tile[tx0 + 0][dr]);
                __hip_bfloat16 b1 = __float2bfloat16(tile[tx0 + 1][dr]);
                __hip_bfloat16 b2 = __float2bfloat16(tile[tx0 + 2][dr]);
                __hip_bfloat16 b3 = __float2bfloat16(tile[tx0 + 3][dr]);
                ushort4 pk;
                pk.x = *(unsigned short*)&b0; pk.y = *(unsigned short*)&b1;
                pk.z = *(unsigned short*)&b2; pk.w = *(unsigned short*)&b3;
                *(ushort4*)&WkvbT[(size_t)(c0 + dr) * KV_RANK + r0 + tx0] = pk;
            }
            __syncthreads();
        }
        return;
    }

    const bool is_q = (bid < 192);
    const int m0 = (is_q ? (bid / 24) : ((bid - 192) / 3)) * 256;
    const int n0 = (is_q ? (bid % 24) : ((bid - 192) % 3)) * 256;

    f32x4 acc[8][4];
    #pragma unroll
    for (int mi = 0; mi < 8; ++mi)
        #pragma unroll
        for (int ni = 0; ni < 4; ++ni) acc[mi][ni] = (f32x4){0.f, 0.f, 0.f, 0.f};

    gemm256_core(A, HID_DIM, is_q ? BtQ : BtKVA, HID_DIM, m0, n0, 0,
                 HID_DIM / 128, lds, acc);

    const int w = t >> 6, L = t & 63;
    const int lane15 = L & 15, quad = L >> 4;
    const int wr = w >> 2, wc = w & 3;
    const int ns = n0 + wc * 64;

    if (is_q) {
        const bool do_rope = ((ns % 192) == 128);   // 64-strip == rope dims of a head
        float bv[4];
        #pragma unroll
        for (int ni = 0; ni < 4; ++ni) bv[ni] = bq[ns + ni * 16 + lane15];

        #pragma unroll
        for (int mi = 0; mi < 8; ++mi) {
            const int rbase = m0 + wr * 128 + mi * 16 + quad * 4;
            float vv[4][4];
            #pragma unroll
            for (int ni = 0; ni < 4; ++ni)
                #pragma unroll
                for (int p = 0; p < 4; ++p) vv[ni][p] = acc[mi][ni][p] + bv[ni];
            if (do_rope) {
                #pragma unroll
                for (int ni = 0; ni < 2; ++ni) {
                    const int dd = ni * 16 + lane15;
                    #pragma unroll
                    for (int p = 0; p < 4; ++p) {
                        const int srow = rbase + p;
                        const float c0 = cosb[srow * ROPE_D + dd];
                        const float c1 = cosb[srow * ROPE_D + dd + 32];
                        const float s0 = sinb[srow * ROPE_D + dd];
                        const float s1 = sinb[srow * ROPE_D + dd + 32];
                        const float x0 = vv[ni][p], x1 = vv[ni + 2][p];
                        vv[ni][p]     = x0 * c0 - x1 * s0;
                        vv[ni + 2][p] = x1 * c1 + x0 * s1;
                    }
                }
            }
            #pragma unroll
            for (int ni = 0; ni < 4; ++ni) {
                const int c = ns + ni * 16 + lane15;
                #pragma unroll
                for (int p = 0; p < 4; ++p)
                    C[(size_t)(rbase + p) * NQK + c] = __float2bfloat16(vv[ni][p] * ATT_SCALE);
            }
        }
    } else if (ns < KV_RANK) {
        // kvlat strips (all 64 cols < 512)
        float bv[4];
        #pragma unroll
        for (int ni = 0; ni < 4; ++ni) bv[ni] = bkva[ns + ni * 16 + lane15];
        #pragma unroll
        for (int mi = 0; mi < 8; ++mi) {
            const int s = m0 + wr * 128 + mi * 16 + quad * 4;
            #pragma unroll
            for (int ni = 0; ni < 4; ++ni) {
                const int c = ns + ni * 16 + lane15;
                #pragma unroll
                for (int p = 0; p < 4; ++p)
                    kvlat[(size_t)(s + p) * KV_RANK + c] =
                        __float2bfloat16(acc[mi][ni][p] + bv[ni]);
            }
        }
    } else if (ns == KV_RANK) {
        // k-RoPE strip: cols 512..575; pairs (512+d, 544+d), d = ni*16+lane15
        #pragma unroll
        for (int mi = 0; mi < 8; ++mi) {
            const int sb = m0 + wr * 128 + mi * 16 + quad * 4;
            #pragma unroll
            for (int ni = 0; ni < 2; ++ni) {
                const int d = ni * 16 + lane15;
                const float ba = bkva[512 + d], bb = bkva[544 + d];
                #pragma unroll
                for (int p = 0; p < 4; ++p) {
                    const int s = sb + p;
                    const float a = acc[mi][ni][p] + ba;
                    const float b = acc[mi][ni + 2][p] + bb;
                    const float c0 = cosb[s * ROPE_D + d], c1 = cosb[s * ROPE_D + d + 32];
                    const float s0 = sinb[s * ROPE_D + d], s1 = sinb[s * ROPE_D + d + 32];
                    kr[(size_t)s * ROPE_D + d]      = __float2bfloat16(a * c0 - b * s0);
                    kr[(size_t)s * ROPE_D + d + 32] = __float2bfloat16(b * c1 + a * s1);
                }
            }
        }
    }
    // ns >= 576: padding strips, no store
}

// ---------------------------------------------------------------------------
// kv up-proj GEMM, 256x256 8-phase core; split epilogue kn + transposed V.
// ---------------------------------------------------------------------------
__global__ __launch_bounds__(512)
void gemm_kv256(const __hip_bfloat16* __restrict__ A,
                const __hip_bfloat16* __restrict__ Bt,
                __hip_bfloat16* __restrict__ kn,
                __hip_bfloat16* __restrict__ vt)
{
    __shared__ __hip_bfloat16 lds[65536];
    const int m0 = blockIdx.y * 256, n0 = blockIdx.x * 256;
    f32x4 acc[8][4];
    #pragma unroll
    for (int mi = 0; mi < 8; ++mi)
        #pragma unroll
        for (int ni = 0; ni < 4; ++ni) acc[mi][ni] = (f32x4){0.f, 0.f, 0.f, 0.f};

    gemm256_core(A, KV_RANK, Bt, KV_RANK, m0, n0, 0, KV_RANK / 128, lds, acc);

    const int t = threadIdx.x;
    const int w = t >> 6, L = t & 63;
    const int lane15 = L & 15, quad = L >> 4;
    const int wr = w >> 2, wc = w & 3;
    const int ns = n0 + wc * 64;

    #pragma unroll
    for (int mi = 0; mi < 8; ++mi) {
        const int rbase = m0 + wr * 128 + mi * 16 + quad * 4;
        #pragma unroll
        for (int ni = 0; ni < 4; ++ni) {
            const int c = ns + ni * 16 + lane15;
            const int h = c >> 8, d = c & 255;
            if (d < NOPE) {
                #pragma unroll
                for (int p = 0; p < 4; ++p)
                    kn[(size_t)(rbase + p) * KNW + h * NOPE + d] = __float2bfloat16(acc[mi][ni][p]);
            } else {
                ushort4 pk;
                __hip_bfloat16 b0 = __float2bfloat16(acc[mi][ni][0]);
                __hip_bfloat16 b1 = __float2bfloat16(acc[mi][ni][1]);
                __hip_bfloat16 b2 = __float2bfloat16(acc[mi][ni][2]);
                __hip_bfloat16 b3 = __float2bfloat16(acc[mi][ni][3]);
                pk.x = *(unsigned short*)&b0; pk.y = *(unsigned short*)&b1;
                pk.z = *(unsigned short*)&b2; pk.w = *(unsigned short*)&b3;
                *(ushort4*)(vt + (size_t)(h * VD + (d - NOPE)) * S_LEN + rbase) = pk;
            }
        }
    }
}

// ---------------------------------------------------------------------------
// Split-K GEMM, 256x256 8-phase core, BF16 partial epilogue (R10-verified:
// absmax unchanged at 0.0078125; halves partial traffic).
// ---------------------------------------------------------------------------
__global__ __launch_bounds__(512)
void gemm_partial256(const __hip_bfloat16* __restrict__ A, int lda,
                     const __hip_bfloat16* __restrict__ Bt, int ldbt,
                     __hip_bfloat16* __restrict__ P, int ldp, size_t zstride, int KL)
{
    __shared__ __hip_bfloat16 lds[65536];
    const int m0 = blockIdx.y * 256, n0 = blockIdx.x * 256;
    const int z  = blockIdx.z;
    f32x4 acc[8][4];
    #pragma unroll
    for (int mi = 0; mi < 8; ++mi)
        #pragma unroll
        for (int ni = 0; ni < 4; ++ni) acc[mi][ni] = (f32x4){0.f, 0.f, 0.f, 0.f};

    gemm256_core(A, lda, Bt, ldbt, m0, n0, z * KL, KL / 128, lds, acc);

    const int t = threadIdx.x;
    const int w = t >> 6, L = t & 63;
    const int lane15 = L & 15, quad = L >> 4;
    const int wr = w >> 2, wc = w & 3;
    __hip_bfloat16* Pz = P + (size_t)z * zstride;

    #pragma unroll
    for (int mi = 0; mi < 8; ++mi) {
        const int rbase = m0 + wr * 128 + mi * 16 + quad * 4;
        #pragma unroll
        for (int ni = 0; ni < 4; ++ni) {
            const int c = n0 + wc * 64 + ni * 16 + lane15;
            #pragma unroll
            for (int p = 0; p < 4; ++p)
                Pz[(size_t)(rbase + p) * ldp + c] = __float2bfloat16(acc[mi][ni][p]);
        }
    }
}

// ---------------------------------------------------------------------------
// Wo reduce: out = P0 + P1 + P2 + P3 + bo  (bf16 partials in, fp32 out).
// ---------------------------------------------------------------------------
__device__ __forceinline__ float b2f(unsigned short u) {
    __hip_bfloat16 h = *(__hip_bfloat16*)&u;
    return __bfloat162float(h);
}

__global__ __launch_bounds__(256)
void wo_reduce4(const __hip_bfloat16* __restrict__ P, const float* __restrict__ bo,
                float* __restrict__ out)
{
    const size_t i = (size_t)blockIdx.x * 256 + threadIdx.x;  // 4-elem index
    const size_t zs = (size_t)S_LEN * OUT_HID;
    ushort4 a = ((const ushort4*)P)[i];
    ushort4 b = ((const ushort4*)(P + zs))[i];
    ushort4 c = ((const ushort4*)(P + 2 * zs))[i];
    ushort4 d = ((const ushort4*)(P + 3 * zs))[i];
    const int col = (int)((i * 4) & (OUT_HID - 1));
    float4 bb = *(const float4*)(bo + col);
    float4 o;
    o.x = b2f(a.x) + b2f(b.x) + b2f(c.x) + b2f(d.x) + bb.x;
    o.y = b2f(a.y) + b2f(b.y) + b2f(c.y) + b2f(d.y) + bb.y;
    o.z = b2f(a.z) + b2f(b.z) + b2f(c.z) + b2f(d.z) + bb.z;
    o.w = b2f(a.w) + b2f(b.w) + b2f(c.w) + b2f(d.w) + bb.w;
    ((float4*)out)[i] = o;
}

// ---------------------------------------------------------------------------
// MFMA sliding-window attention with sink. T14 async-stage split (R8):
// K/V chunk loads issued into registers one chunk early; ds_write after the
// barrier. Same barrier structure & buffers as the verified R2 version.
// ---------------------------------------------------------------------------
#define SS 170     // fp32 S stride
#define SP 168     // bf16 P stride
#define KSTR 200   // staged K row stride (bf16), 400B, 16B-aligned
#define VSTR 40    // staged V row stride (bf16), 80B, 16B-aligned

__global__ __launch_bounds__(256)
void attn_mfma2(const __hip_bfloat16* __restrict__ q,
                const __hip_bfloat16* __restrict__ kn,
                const __hip_bfloat16* __restrict__ kr,
                const __hip_bfloat16* __restrict__ vt,
                const float* __restrict__ sinks,
                __hip_bfloat16* __restrict__ out)
{
    __shared__ float lds_s[32 * SS];
    __shared__ __hip_bfloat16 lds_p[32 * SP];
    __shared__ __hip_bfloat16 lds_kv[32 * KSTR];   // also used as [128][VSTR]

    const int h  = blockIdx.y;
    const int q0 = blockIdx.x * 32;
    const int t  = threadIdx.x;
    const int w  = t >> 6;
    const int L  = t & 63;
    const int lane15 = L & 15, quad = L >> 4;
    const int wm = (w & 1) * 16;
    const int wn = (w >> 1) * 16;

    int lo = q0 - SW + 1; if (lo < 0) lo = 0;
    const int cb = lo & ~31;
    const int nc = ((q0 - cb) >> 5) + 1;    // 1..5

    // T14 staging registers + helpers
    bf16x8 kreg[3];
    auto issueK = [&](int c0) {
        #pragma unroll
        for (int i = 0; i < 3; ++i) {
            const int e = t + i * 256;
            const int row = e / 24, slot = e % 24;
            const int j = c0 + row;
            const __hip_bfloat16* g = (slot < 16)
                ? kn + (size_t)j * KNW + h * NOPE + slot * 8
                : kr + (size_t)j * ROPE_D + (slot - 16) * 8;
            kreg[i] = *(const bf16x8*)(const void*)g;
        }
    };
    auto writeK = [&]() {
        #pragma unroll
        for (int i = 0; i < 3; ++i) {
            const int e = t + i * 256;
            const int row = e / 24, slot = e % 24;
            *(bf16x8*)(void*)(lds_kv + row * KSTR + slot * 8) = kreg[i];
        }
    };
    bf16x8 vreg[2];
    auto issueV = [&](int c0) {
        #pragma unroll
        for (int i = 0; i < 2; ++i) {
            const int e = t + i * 256;
            const int row = e >> 2, slot = e & 3;
            vreg[i] = *(const bf16x8*)(const void*)(
                vt + (size_t)(h * VD + row) * S_LEN + c0 + slot * 8);
        }
    };
    auto writeV = [&]() {
        #pragma unroll
        for (int i = 0; i < 2; ++i) {
            const int e = t + i * 256;
            const int row = e >> 2, slot = e & 3;
            *(bf16x8*)(void*)(lds_kv + row * VSTR + slot * 8) = vreg[i];
        }
    };

    bf16x8 qf[6];
    {
        const __hip_bfloat16* qrow = q + (size_t)(q0 + wm + lane15) * NQK + h * QKD;
        #pragma unroll
        for (int kk = 0; kk < 6; ++kk)
            qf[kk] = *(const bf16x8*)(const void*)(qrow + kk * 32 + quad * 8);
    }

    // ---- QK^T per chunk (K loads issued one chunk early) ----
    issueK(cb);
    for (int cc = 0; cc < nc; ++cc) {
        const int c0 = cb + cc * 32;
        __syncthreads();                 // previous chunk's LDS fully consumed
        writeK();
        if (cc + 1 < nc) issueK(cb + (cc + 1) * 32);   // fly under barrier+MFMA
        __syncthreads();

        f32x4 s = (f32x4){0.f, 0.f, 0.f, 0.f};
        #pragma unroll
        for (int kk = 0; kk < 6; ++kk) {
            bf16x8 bf = *(const bf16x8*)(const void*)(lds_kv + (wn + lane15) * KSTR + kk * 32 + quad * 8);
            s = __builtin_amdgcn_mfma_f32_16x16x32_bf16(qf[kk], bf, s, 0, 0, 0);
        }
        const int j = c0 + wn + lane15;
        #pragma unroll
        for (int p = 0; p < 4; ++p) {
            const int i = q0 + wm + quad * 4 + p;
            const bool ok = (j <= i) && (i - j < SW);
            lds_s[(wm + quad * 4 + p) * SS + cc * 32 + wn + lane15] = ok ? s[p] : NEG_INF;
        }
    }
    __syncthreads();

    issueV(cb);                          // V chunk 0 loads fly under softmax

    {
        const int r = t >> 3, g = t & 7;
        const int ncols = nc * 32;
        const float sink = sinks[h];
        float mx = sink;
        for (int c = g; c < ncols; c += 8)
            mx = fmaxf(mx, lds_s[r * SS + c]);
        #pragma unroll
        for (int off = 1; off < 8; off <<= 1)
            mx = fmaxf(mx, __shfl_xor(mx, off));
        float sum = 0.f;
        for (int c = g; c < ncols; c += 8) {
            float e = __expf(lds_s[r * SS + c] - mx);
            lds_s[r * SS + c] = e;
            sum += e;
        }
        #pragma unroll
        for (int off = 1; off < 8; off <<= 1)
            sum += __shfl_xor(sum, off);
        const float inv = 1.0f / (sum + __expf(sink - mx));
        for (int c = g; c < ncols; c += 8)
            lds_p[r * SP + c] = __float2bfloat16(lds_s[r * SS + c] * inv);
    }

    // ---- PV per chunk (V loads issued one chunk early) ----
    f32x4 oacc[4];
    #pragma unroll
    for (int ni = 0; ni < 4; ++ni) oacc[ni] = (f32x4){0.f, 0.f, 0.f, 0.f};

    for (int cc = 0; cc < nc; ++cc) {
        __syncthreads();                 // softmax done (cc==0) / prev PV done
        writeV();
        if (cc + 1 < nc) issueV(cb + (cc + 1) * 32);
        __syncthreads();

        bf16x8 ap = *(const bf16x8*)(const void*)(lds_p + (wm + lane15) * SP + cc * 32 + quad * 8);
        #pragma unroll
        for (int ni = 0; ni < 4; ++ni) {
            bf16x8 bv = *(const bf16x8*)(const void*)(lds_kv + ((w >> 1) * 64 + ni * 16 + lane15) * VSTR + quad * 8);
            oacc[ni] = __builtin_amdgcn_mfma_f32_16x16x32_bf16(ap, bv, oacc[ni], 0, 0, 0);
        }
    }

    #pragma unroll
    for (int ni = 0; ni < 4; ++ni) {
        const int col = h * VD + (w >> 1) * 64 + ni * 16 + lane15;
        #pragma unroll
        for (int p = 0; p < 4; ++p) {
            const int row = q0 + wm + quad * 4 + p;
            out[(size_t)row * (NH * VD) + col] = __float2bfloat16(oacc[ni][p]);
        }
    }
}

// ---------------------------------------------------------------------------
extern "C" void kernel_launch(void* const* d_in, const int* in_sizes, int n_in,
                              void* d_out, int out_size, void* d_ws, size_t ws_size,
                              hipStream_t stream) {
    const float* hidden = (const float*)d_in[0];
    const float* cosb   = (const float*)d_in[1];
    const float* sinb   = (const float*)d_in[2];
    const float* Wq     = (const float*)d_in[3];
    const float* bq     = (const float*)d_in[4];
    const float* Wkva   = (const float*)d_in[5];
    const float* bkva   = (const float*)d_in[6];
    const float* Wkvb   = (const float*)d_in[7];
    const float* Wo     = (const float*)d_in[8];
    const float* bo     = (const float*)d_in[9];
    const float* sinks  = (const float*)d_in[10];
    float* out = (float*)d_out;

    // workspace, 139.0 MB. Alias:
    //   WoP (33.6 MB bf16 partials) <- q_bf (25.2 MB) + hid_bf head, dead after attn
    uint8_t* p = (uint8_t*)d_ws;
    __hip_bfloat16* attn_bf = (__hip_bfloat16*)p; p += (size_t)S_LEN * NH * VD * 2;   // 16.78 MB
    __hip_bfloat16* WoT     = (__hip_bfloat16*)p; p += (size_t)OUT_HID * (NH*VD) * 2; // 16.78 MB
    __hip_bfloat16* q_bf    = (__hip_bfloat16*)p; p += (size_t)S_LEN * NQK * 2;       // 25.17 MB
    __hip_bfloat16* hid_bf  = (__hip_bfloat16*)p; p += (size_t)S_LEN * HID_DIM * 2;   //  8.39 MB
    __hip_bfloat16* WqT     = (__hip_bfloat16*)p; p += (size_t)NQK * HID_DIM * 2;     // 25.17 MB
    __hip_bfloat16* WkvaT   = (__hip_bfloat16*)p; p += (size_t)640 * HID_DIM * 2;     //  2.62 MB
    __hip_bfloat16* WkvbT   = (__hip_bfloat16*)p; p += (size_t)KVN * KV_RANK * 2;     //  8.39 MB
    __hip_bfloat16* kn_bf   = (__hip_bfloat16*)p; p += (size_t)S_LEN * KNW * 2;       // 16.78 MB
    __hip_bfloat16* vt_bf   = (__hip_bfloat16*)p; p += (size_t)S_LEN * NH * VD * 2;   // 16.78 MB
    __hip_bfloat16* kr_bf   = (__hip_bfloat16*)p; p += (size_t)S_LEN * ROPE_D * 2;    //  0.26 MB
    __hip_bfloat16* kvlat   = (__hip_bfloat16*)p; p += (size_t)S_LEN * KV_RANK * 2;   //  2.10 MB
    __hip_bfloat16* WoP = q_bf;    // after attn (33.6 MB bf16 < q_bf+hid_bf)

    // 1. conversions: hidden (4096) + Wq (3072) + Wkva (288) + Wo (2048) = 9504
    prep<<<9504, 256, 0, stream>>>(hidden, hid_bf, Wq, WqT, Wkva, WkvaT, Wo, WoT);

    // 2. merged: q-proj (192) + ckv-proj (24) + Wkvb transpose (40) = 256
    gemm_q_ckv<<<256, 512, 0, stream>>>(
        hid_bf, WqT, WkvaT, bq, bkva, cosb, sinb, q_bf, kvlat, kr_bf,
        Wkvb, WkvbT);

    // 3. kv up-proj: kn + transposed V  [256^2 8-phase, 256 blocks]
    gemm_kv256<<<dim3(KVN / 256, S_LEN / 256), 512, 0, stream>>>(
        kvlat, WkvbT, kn_bf, vt_bf);

    // 4. attention (MFMA, LDS-staged K/V, T14 async staging)
    attn_mfma2<<<dim3(S_LEN / 32, NH), 256, 0, stream>>>(
        q_bf, kn_bf, kr_bf, vt_bf, sinks, attn_bf);

    // 5. Wo partials: split-K x4, bf16 partials (256 blocks, 256^2 8-phase)
    gemm_partial256<<<dim3(OUT_HID / 256, S_LEN / 256, 4), 512, 0, stream>>>(
        attn_bf, NH * VD, WoT, NH * VD, WoP, OUT_HID, (size_t)S_LEN * OUT_HID, 1024);

    // 6. out = P0+P1+P2+P3 + bo
    wo_reduce4<<<(S_LEN * OUT_HID / 4) / 256, 256, 0, stream>>>(WoP, bo, out);
}